// Round 10
// baseline (164.360 us; speedup 1.0000x reference)
//
#include <hip/hip_runtime.h>
#include <stdint.h>

typedef __attribute__((ext_vector_type(8))) _Float16 half8;
typedef __attribute__((ext_vector_type(2))) _Float16 h2;
typedef __attribute__((ext_vector_type(4))) float f32x4;

#define NCHUNK 32     // 4096 t / 128 t per chunk (2 i-slices per chunk)

static __device__ __forceinline__ unsigned short f2h(float f) {
  return __builtin_bit_cast(unsigned short, (_Float16)f);
}
// async global->LDS, 16 B per lane; lds dest must be wave-uniform base
static __device__ __forceinline__ void gload16(const void* g, void* l) {
  __builtin_amdgcn_global_load_lds((const __attribute__((address_space(1))) void*)g,
                                   (__attribute__((address_space(3))) void*)l, 16, 0, 0);
}

// ---- phase 1 (fused, verified r5-r9): Bs = sym(sum_w wgt[w]*mix[w]) -> f16 [64][4096] ----
__global__ __launch_bounds__(1024) void prep_kernel(const float* __restrict__ mix,
                                                    const float* __restrict__ wgt,
                                                    unsigned short* __restrict__ Bp) {
  __shared__ float T[4096];
  const int k   = blockIdx.x;
  const int tid = threadIdx.x;
  const float4* m4 = (const float4*)mix + (size_t)k * 1024 + tid;
  float4 a = {0.f, 0.f, 0.f, 0.f};
#pragma unroll
  for (int w = 0; w < 32; ++w) {
    const float s = wgt[w];
    const float4 v = m4[(size_t)w * 65536];
    a.x += s * v.x; a.y += s * v.y; a.z += s * v.z; a.w += s * v.w;
  }
  *(float4*)(&T[tid * 4]) = a;
  __syncthreads();
  ushort4 r;
#pragma unroll
  for (int e = 0; e < 4; ++e) {
    const int t = tid * 4 + e, i = t >> 6, j = t & 63;
    float v;
    if (i < j)       v = T[t] + T[(j << 6) | i];
    else if (i == j) v = T[t];
    else             v = 0.f;
    ((unsigned short*)&r)[e] = f2h(v);
  }
  ((ushort4*)Bp)[k * 1024 + tid] = r;
}

// ---- phase 2: out[z][k] = sum_t V[z,t]*Bs[k,t], V generated in-register ----
// r5 skeleton (512 thr, 8 waves = 4 wz x 2 wk, wave 64z x 32k, depth-2 DMA
// staging into 3 buffers, vmcnt(2), XOR-16B swizzle, h=0 skip for c>=16)
// with ONE structural delta: quarter-chunk phases with PURE MFMA clusters.
// Per phase (il,h): region R issues 2 ds_read_b128 (B) and builds ALL four
// A fragments via v_pk_mul_f16 BEFORE the barrier; after s_barrier +
// lgkmcnt(0), the cluster is 8 back-to-back MFMAs with zero VALU/DS inside
// (m201/m233 property: back-to-back MFMA reaches 86% peak; setprio pays only
// on this structure). sched_barrier(0) pins stop the compiler re-sinking
// the A-gen into the cluster (rule #18).
__global__ __launch_bounds__(512, 4) void gemm_kernel(const float* __restrict__ X,
                                                      const unsigned short* __restrict__ Bp,
                                                      float* __restrict__ out) {
  __shared__ unsigned short ldsB[3][64 * 128];    // 3 x 16 KB = 48 KB
  __shared__ unsigned short sH[2][2][256];        // [buf][il][dword*2+half] 2 KB

  const int tid  = threadIdx.x;
  const int lane = tid & 63;
  const int wv   = tid >> 6;    // wave 0..7
  const int wz   = wv >> 1;     // z-group 0..3 -> z rows wz*64..+63
  const int wk   = wv & 1;      // k-half 0/1 -> k cols wk*32..+31
  const int m    = lane & 15;
  const int q    = lane >> 4;
  const int zblk = blockIdx.x * 256;

  // stage chunk ct into ldsB[bf]: 8 waves x 2 segs x 1 KB; linear dest,
  // inverse-swizzled source unit u = (lane&15) ^ (row&15)   [verified r2-r9]
  auto stageB = [&](int ct, int bf) {
#pragma unroll
    for (int it = 0; it < 2; ++it) {
      const int seg = wv * 2 + it;
      const int row = seg * 4 + (lane >> 4);
      const int u   = (lane & 15) ^ (row & 15);
      gload16(Bp + (size_t)row * 4096 + ct * 128 + u * 8,
              &ldsB[bf][seg * 512]);
    }
  };

  // s-broadcast publish (verified r4/r5): dword d = wz*32+m*2+fd,
  // writer tid<256: z_local = tid; bits wz=tid[7:6], fd=tid[5], hf=tid[4], m=tid[3:0]
  auto publishS = [&](int bf, float2 xp) {
    if (tid < 256) {
      const int d  = (tid >> 6) * 32 + (tid & 15) * 2 + ((tid >> 5) & 1);
      const int hf = (tid >> 4) & 1;
      sH[bf][0][d * 2 + hf] = f2h(xp.x);
      sH[bf][1][d * 2 + hf] = f2h(xp.y);
    }
  };

  // ---- prologue: B chunks 0,1 + s chunk 0 ----
  stageB(0, 0);
  stageB(1, 1);
  {
    float2 xp0 = {0.f, 0.f};
    if (tid < 256) xp0 = *(const float2*)(X + (size_t)(zblk + tid) * 64);
    publishS(0, xp0);
  }

  // ---- per-lane f16 j-cache: jh[f][h*4+e] = {x[z(f,m), h*32+q*8+2e], x[..,+1]} ----
  h2 jh[4][8];
  {
    const float4* X4g = (const float4*)X;
#pragma unroll
    for (int f = 0; f < 4; ++f) {
      const int zg = zblk + wz * 64 + f * 16 + m;
#pragma unroll
      for (int h = 0; h < 2; ++h) {
        const float4 a = X4g[zg * 16 + h * 8 + q * 2];
        const float4 b = X4g[zg * 16 + h * 8 + q * 2 + 1];
        jh[f][h * 4 + 0] = h2{(_Float16)a.x, (_Float16)a.y};
        jh[f][h * 4 + 1] = h2{(_Float16)a.z, (_Float16)a.w};
        jh[f][h * 4 + 2] = h2{(_Float16)b.x, (_Float16)b.y};
        jh[f][h * 4 + 3] = h2{(_Float16)b.z, (_Float16)b.w};
      }
    }
  }

  f32x4 acc[4][2];
#pragma unroll
  for (int f = 0; f < 4; ++f) {
    acc[f][0] = f32x4{0.f, 0.f, 0.f, 0.f};
    acc[f][1] = f32x4{0.f, 0.f, 0.f, 0.f};
  }

  __syncthreads();   // one-time full drain: chunks 0,1 staged, sH[0] ready

  int bufc = 0;
  for (int c = 0; c < NCHUNK; ++c) {
    const int cn = (c + 1) & (NCHUNK - 1);
    // next s-broadcast load (oldest in-loop VMEM; waves 0..3 only)
    float2 spre = {0.f, 0.f};
    if (tid < 256)
      spre = *(const float2*)(X + (size_t)(zblk + tid) * 64 + cn * 2);
    // async-stage chunk c+2 into the third buffer (in flight across barriers)
    int bs = bufc + 2; if (bs >= 3) bs -= 3;
    stageB((c + 2) & (NCHUNK - 1), bs);

    const unsigned short* Bl = &ldsB[bufc][0];
    const bool full = (c < 16);

#pragma unroll
    for (int il = 0; il < 2; ++il) {
      // sv read + splats live across both h-phases of this il
      const uint2 sv = *(const uint2*)(&sH[c & 1][il][wz * 64 + m * 4]);
      h2 s2f[4];
      s2f[0] = __builtin_bit_cast(h2, __builtin_amdgcn_perm(sv.x, sv.x, 0x01000100u));
      s2f[1] = __builtin_bit_cast(h2, __builtin_amdgcn_perm(sv.x, sv.x, 0x03020302u));
      s2f[2] = __builtin_bit_cast(h2, __builtin_amdgcn_perm(sv.y, sv.y, 0x01000100u));
      s2f[3] = __builtin_bit_cast(h2, __builtin_amdgcn_perm(sv.y, sv.y, 0x03020302u));
#pragma unroll
      for (int h = 0; h < 2; ++h) {
        if (h == 0 && !full) continue;   // upper-triangular skip (exact, uniform)

        // ---- region R: issue B reads + build ALL A fragments ----
        const int u = ((il << 3) + (h << 2) + q) ^ m;   // swizzled 16B unit
        const unsigned short* bb = Bl + (wk * 32 + m) * 128 + u * 8;
        const half8 b0 = *(const half8*)(const void*)(bb);            // k = wk*32+m
        const half8 b1 = *(const half8*)(const void*)(bb + 16 * 128); // k = +16
        union { unsigned u[4]; half8 v; } A0, A1, A2, A3;
#pragma unroll
        for (int e = 0; e < 4; ++e) {
          A0.u[e] = __builtin_bit_cast(unsigned, s2f[0] * jh[0][h * 4 + e]);
          A1.u[e] = __builtin_bit_cast(unsigned, s2f[1] * jh[1][h * 4 + e]);
          A2.u[e] = __builtin_bit_cast(unsigned, s2f[2] * jh[2][h * 4 + e]);
          A3.u[e] = __builtin_bit_cast(unsigned, s2f[3] * jh[3][h * 4 + e]);
        }
        __builtin_amdgcn_sched_barrier(0);

        // ---- phase barrier A + operand fence ----
        __builtin_amdgcn_s_barrier();
        asm volatile("s_waitcnt lgkmcnt(0)" ::: "memory");
        __builtin_amdgcn_sched_barrier(0);

        // ---- PURE MFMA cluster: 8 back-to-back, zero VALU/DS inside ----
        __builtin_amdgcn_s_setprio(1);
        acc[0][0] = __builtin_amdgcn_mfma_f32_16x16x32_f16(A0.v, b0, acc[0][0], 0, 0, 0);
        acc[0][1] = __builtin_amdgcn_mfma_f32_16x16x32_f16(A0.v, b1, acc[0][1], 0, 0, 0);
        acc[1][0] = __builtin_amdgcn_mfma_f32_16x16x32_f16(A1.v, b0, acc[1][0], 0, 0, 0);
        acc[1][1] = __builtin_amdgcn_mfma_f32_16x16x32_f16(A1.v, b1, acc[1][1], 0, 0, 0);
        acc[2][0] = __builtin_amdgcn_mfma_f32_16x16x32_f16(A2.v, b0, acc[2][0], 0, 0, 0);
        acc[2][1] = __builtin_amdgcn_mfma_f32_16x16x32_f16(A2.v, b1, acc[2][1], 0, 0, 0);
        acc[3][0] = __builtin_amdgcn_mfma_f32_16x16x32_f16(A3.v, b0, acc[3][0], 0, 0, 0);
        acc[3][1] = __builtin_amdgcn_mfma_f32_16x16x32_f16(A3.v, b1, acc[3][1], 0, 0, 0);
        __builtin_amdgcn_s_setprio(0);
        __builtin_amdgcn_sched_barrier(0);

        if (il == 1 && h == 1) {
          // end of chunk: publish next s-broadcast, counted waits.
          // vmcnt(2): chunk c+1's 2 stage-DMAs done; c+2's 2 stay in flight
          // ACROSS the barrier. lgkmcnt(0): sH writes visible after barrier.
          publishS(cn & 1, spre);
          asm volatile("s_waitcnt vmcnt(2)" ::: "memory");
          asm volatile("s_waitcnt lgkmcnt(0)" ::: "memory");
        }
        // ---- phase barrier B ----
        __builtin_amdgcn_s_barrier();
        __builtin_amdgcn_sched_barrier(0);
      }
    }
    bufc = (bufc + 1 == 3) ? 0 : bufc + 1;
  }

  // ---- epilogue: C/D layout col=lane&15 (k), row=q*4+r (z)  [verified r2] ----
#pragma unroll
  for (int f = 0; f < 4; ++f) {
    const int zr = zblk + wz * 64 + f * 16 + q * 4;
#pragma unroll
    for (int g = 0; g < 2; ++g)
#pragma unroll
      for (int r = 0; r < 4; ++r)
        out[(size_t)(zr + r) * 64 + wk * 32 + g * 16 + m] = acc[f][g][r];
  }
}

extern "C" void kernel_launch(void* const* d_in, const int* in_sizes, int n_in,
                              void* d_out, int out_size, void* d_ws, size_t ws_size,
                              hipStream_t stream) {
  const float* X   = (const float*)d_in[0];   // [131072, 64]
  const float* mix = (const float*)d_in[1];   // [32, 64, 64, 64]
  const float* wgt = (const float*)d_in[2];   // [32]
  float* out = (float*)d_out;                 // [131072, 64]
  unsigned short* Bp = (unsigned short*)d_ws; // 512 KB: Bs f16 [64][4096]

  prep_kernel<<<64, 1024, 0, stream>>>(mix, wgt, Bp);
  gemm_kernel<<<512, 512, 0, stream>>>(X, Bp, out);
}